// Round 23
// baseline (118.821 us; speedup 1.0000x reference)
//
#include <hip/hip_runtime.h>

// VQ-VAE codebook lookup:
//   z: (64, 128, 32, 32) fp32, emb: (512, 128) fp32
//   outputs (concat in d_out, fp32): z_q (8388608) | loss (1) | indices (65536)
//
// Index output validated vs NUMPY fp32 reference (scalar threshold 10.24).
// Strategy (validated r2-r22): 1-MFMA bf16 distance argmin (zh*eh; dot error
// <= ~8e-5 << GAP_THR/2) with uint-packed keys + near-tie flags (GAP 4e-4) +
// numpy-fp32-replica fixup on flagged rows. z_q/loss from pre-fixup codes.
//
// R23 (r22 unroll null; 2n x 2k shape exhausted at 98.8us x3 runs): revive
// r10's FASTEST-measured dist geometry (2048 blocks x 4 waves, k-QUARTER
// split over a 32-row tile; dist 55us even with 3-MFMA) and fuse in all
// later wins: 1-MFMA (r19), A-frags direct from z (4 waves read identical
// addresses -> L1 broadcast; no zsplit), fused z_q/loss epilogue (r12),
// XCD swizzle, 4-way exact top-2 packed-key merge (r10-validated).
// Pipeline: memset -> prep -> dist -> fixup -> fin (5 dispatches).

#define D_DIM 128
#define HW    1024
#define GAP_THR 4e-4f
#define FLAG_CAP 16384

typedef short short8 __attribute__((ext_vector_type(8)));
typedef float f32x16 __attribute__((ext_vector_type(16)));

union U8 { unsigned int u[4]; short8 s; uint4 q; };

__device__ __forceinline__ unsigned short f2bf(float v) {   // RNE fp32->bf16
    unsigned int u = __builtin_bit_cast(unsigned int, v);
    return (unsigned short)((u + 0x7fffu + ((u >> 16) & 1u)) >> 16);
}
__device__ __forceinline__ unsigned int umn(unsigned int a, unsigned int b) {
    return a < b ? a : b;
}
__device__ __forceinline__ unsigned int umx(unsigned int a, unsigned int b) {
    return a > b ? a : b;
}

// -------- kernel 0: fused prep: etr (all t) + esplit (t<8192) + se (t<512) --
__global__ void prep_kernel(const float* __restrict__ emb,
                            float* __restrict__ etr,
                            uint4* __restrict__ ebh,
                            float* __restrict__ se) {
    const int t = blockIdx.x * 256 + threadIdx.x;   // 0..65535

    // ---- etr[d][k] = emb[k][d] (transposed codebook, 256 KB) ----
    {
        const int k = t >> 7;
        const int d = t & 127;
        etr[d * 512 + k] = emb[t];
    }

    // ---- esplit: emb -> bf16 B-fragment images [kcol][ks][lane] (hi only) --
    if (t < 8192) {
        const int lane = t & 63;
        const int ks   = (t >> 6) & 7;
        const int kcol = t >> 9;
        const int krow = kcol * 32 + (lane & 31);
        const int d0   = ks * 16 + (lane >> 5) * 8;
        const float* ep = emb + (size_t)krow * D_DIM + d0;
        float v[8];
        #pragma unroll
        for (int j = 0; j < 8; ++j) v[j] = ep[j];
        U8 hh;
        #pragma unroll
        for (int p = 0; p < 4; ++p) {
            const unsigned short h0 = f2bf(v[2*p]), h1 = f2bf(v[2*p+1]);
            hh.u[p] = (unsigned int)h0 | ((unsigned int)h1 << 16);
        }
        ebh[t] = hh.q;
    }

    // ---- se[k] = np.sum(emb[k]**2) fp32-replica (pairwise, 8 accums) ----
    if (t < 512) {
        const float* e = emb + (size_t)t * D_DIM;
        float r[8];
        #pragma unroll
        for (int j = 0; j < 8; ++j) {
            float v = e[j];
            float p = v * v;
            asm("" : "+v"(p));   // force rounded square (no fma contraction)
            r[j] = p;
        }
        for (int i = 8; i < 128; i += 8) {
            #pragma unroll
            for (int j = 0; j < 8; ++j) {
                float v = e[i + j];
                float p = v * v;
                asm("" : "+v"(p));
                r[j] += p;
            }
        }
        se[t] = ((r[0] + r[1]) + (r[2] + r[3])) + ((r[4] + r[5]) + (r[6] + r[7]));
    }
}

// ---- kernel 1: fused dist: 4-wave k-QUARTER split, 1-MFMA argmin + z_q ----
// 2048 blocks x 256 thr. Block = one 32-row tile; wave wid = k-quarter wid.
__launch_bounds__(256, 4)
__global__ void dist_kernel(const float* __restrict__ z,
                            const uint4* __restrict__ ebh,
                            const float* __restrict__ se_g,
                            const float* __restrict__ emb,
                            float* __restrict__ idx_out,
                            unsigned int* __restrict__ flag_cnt,
                            int* __restrict__ flag_list,
                            float* __restrict__ zq,
                            double* __restrict__ loss) {
    __shared__ unsigned int red1[4][32], red2[4][32];
    __shared__ int   li_sh[32];
    __shared__ float ept[D_DIM * 33];   // 32-row transposed emb stage
    __shared__ float lred[4];

    const int tid  = threadIdx.x;
    const int lane = tid & 63;
    const int wid  = tid >> 6;          // k-quarter 0..3
    const int row  = lane & 31;
    // XCD-aware swizzle (T1): 2048 blocks, 8 XCDs, bijective.
    const int bidl = (int)blockIdx.x;
    const int bid  = (bidl & 7) * 256 + (bidl >> 3);
    const int nblk = bid * 32;          // block rows (one image: 1024%32==0)
    const int bimg = nblk >> 10;
    const int hw0  = nblk & 1023;

    // ---- A-frags (hi only): all 4 waves read IDENTICAL addresses (L1) ------
    short8 Ah[8];
    {
        const float* zc = z + (size_t)bimg * (D_DIM * HW) + hw0 + row;
        #pragma unroll
        for (int ks = 0; ks < 8; ++ks) {
            const int d0 = ks * 16 + (lane >> 5) * 8;
            float v[8];
            #pragma unroll
            for (int j = 0; j < 8; ++j) v[j] = zc[(size_t)(d0 + j) * HW];
            U8 hh;
            #pragma unroll
            for (int p = 0; p < 4; ++p) {
                unsigned int hwd;
                asm("v_cvt_pk_bf16_f32 %0, %1, %2" : "=v"(hwd) : "v"(v[2*p]), "v"(v[2*p+1]));
                hh.u[p] = hwd;
            }
            Ah[ks] = hh.s;
        }
    }

    unsigned int b1[16], b2[16];
    #pragma unroll
    for (int j = 0; j < 16; ++j) { b1[j] = 0xFFFFFFFFu; b2[j] = 0xFFFFFFFFu; }

    // ---- sweep this k-quarter's 4 columns, staggered per block -------------
    for (int i = 0; i < 4; ++i) {
        const int   kc   = wid * 4 + ((i + bidl) & 3);   // de-contend L2
        const int   kgl  = kc * 32 + row;
        const float sevp = se_g[kgl] + 0.5f;
        const uint4* pbh = ebh + kc * 512 + lane;

        f32x16 acc;   // single chain, 16 AGPR
        #pragma unroll
        for (int j = 0; j < 16; ++j) acc[j] = 0.f;

        __builtin_amdgcn_s_setprio(1);
        #pragma unroll
        for (int ks = 0; ks < 8; ++ks) {
            U8 bh; bh.q = pbh[ks * 64];
            acc = __builtin_amdgcn_mfma_f32_32x32x16_bf16(Ah[ks], bh.s, acc, 0, 0, 0);
        }
        __builtin_amdgcn_s_setprio(0);

        // fold with uint-packed keys: pd = (se - 2*dot) + 0.5 in (0.25, 1)
        #pragma unroll
        for (int j = 0; j < 16; ++j) {
            const float pd = fmaf(-2.f, acc[j], sevp);
            const unsigned int key =
                (__builtin_bit_cast(unsigned int, pd) & 0xFFFFFE00u) | (unsigned int)kgl;
            const unsigned int m = umn(key, b1[j]);
            b2[j] = umn(umx(key, b1[j]), b2[j]);
            b1[j] = m;
        }
    }

    // ---- per-wave reduce over the 32 k-lanes -------------------------------
    #pragma unroll
    for (int off = 1; off <= 16; off <<= 1) {
        #pragma unroll
        for (int j = 0; j < 16; ++j) {
            const unsigned int o1 = (unsigned int)__shfl_xor((int)b1[j], off);
            const unsigned int o2 = (unsigned int)__shfl_xor((int)b2[j], off);
            const unsigned int m  = umn(b1[j], o1);
            b2[j] = umn(umx(b1[j], o1), umn(b2[j], o2));
            b1[j] = m;
        }
    }

    if ((lane & 31) == 0) {
        const int half = lane >> 5;
        #pragma unroll
        for (int j = 0; j < 16; ++j) {
            // C/D layout (m74/m101): row = (reg&3) + 8*(reg>>2) + 4*(lane>>5)
            const int r = (j & 3) + 8 * (j >> 2) + 4 * half;
            red1[wid][r] = b1[j];
            red2[wid][r] = b2[j];
        }
    }
    __syncthreads();

    // ---- exact top-2 merge over the 4 k-quarters (threads 0..31) -----------
    if (tid < 32) {
        unsigned int m1 = red1[0][tid], m2 = red2[0][tid];
        #pragma unroll
        for (int w = 1; w < 4; ++w) {
            const unsigned int v1 = red1[w][tid];
            const unsigned int v2 = red2[w][tid];
            const unsigned int nm = umn(m1, v1);
            m2 = umn(umn(m2, v2), umx(m1, v1));
            m1 = nm;
        }
        const int n = nblk + tid;
        const int code = (int)(m1 & 511u);
        idx_out[n] = (float)code;
        li_sh[tid] = code;
        const float f1 = __builtin_bit_cast(float, m1 & 0xFFFFFE00u);
        const float f2 = __builtin_bit_cast(float, m2 & 0xFFFFFE00u);
        if (f2 - f1 < GAP_THR) {
            unsigned int p = atomicAdd(flag_cnt, 1u);
            if (p < FLAG_CAP) flag_list[p] = n;
        }
    }
    __syncthreads();   // li_sh visible

    // ---- epilogue: single phase, 32 rows (r12-validated stage/write) -------
    {
        const int p   = tid >> 3;         // row 0..31 (8 threads per row)
        const int sub = tid & 7;
        const float* er = emb + (size_t)li_sh[p] * D_DIM + sub * 16;
        #pragma unroll
        for (int j4 = 0; j4 < 4; ++j4) {
            const float4 v = *(const float4*)(er + j4 * 4);
            const int c = sub * 16 + j4 * 4;
            ept[(c + 0) * 33 + p] = v.x;
            ept[(c + 1) * 33 + p] = v.y;
            ept[(c + 2) * 33 + p] = v.z;
            ept[(c + 3) * 33 + p] = v.w;
        }
    }
    __syncthreads();
    {
        const int p  = tid & 31;          // hw position within tile
        const int c0 = tid >> 5;          // 0..7
        const float* zb2 = z  + (size_t)bimg * (D_DIM * HW) + hw0 + p;
        float*       qb  = zq + (size_t)bimg * (D_DIM * HW) + hw0 + p;
        float lacc = 0.f;
        #pragma unroll
        for (int i = 0; i < 16; ++i) {
            const int c = c0 + i * 8;
            const float v  = ept[c * 33 + p];
            const float zv = zb2[(size_t)c * HW];   // L1-hot (prologue read)
            qb[(size_t)c * HW] = v;
            const float df = v - zv;
            lacc = fmaf(df, df, lacc);
        }
        #pragma unroll
        for (int off = 32; off > 0; off >>= 1) lacc += __shfl_down(lacc, off);
        if (lane == 0) lred[wid] = lacc;
    }
    __syncthreads();
    if (tid == 0)
        atomicAdd(loss, (double)(lred[0] + lred[1] + lred[2] + lred[3]));
}

// ------- kernel 1b: numpy-fp32-replica re-argmin, ONE row per block --------
// thread k owns code k; emb read via TRANSPOSED etr[d][k] -> coalesced.
__launch_bounds__(512)
__global__ void fixup_kernel(const float* __restrict__ z,
                             const float* __restrict__ etr,
                             const unsigned int* __restrict__ flag_cnt,
                             const int* __restrict__ flag_list,
                             const float* __restrict__ se_np,
                             float* __restrict__ idx_out) {
    __shared__ float zrow[D_DIM];
    __shared__ float q[D_DIM];
    __shared__ float rsum[8];
    __shared__ float szs;
    __shared__ float rv[8];
    __shared__ int   rix[8];

    const int tid = threadIdx.x;
    unsigned int cnt = *flag_cnt;
    if (cnt > FLAG_CAP) cnt = FLAG_CAP;

    for (unsigned int f = blockIdx.x; f < cnt; f += gridDim.x) {
        const int row = flag_list[f];
        const int b   = row >> 10;
        const int hw  = row & 1023;
        __syncthreads();   // previous iteration's readers done
        if (tid < D_DIM) {
            float v = z[(size_t)b * (D_DIM * HW) + (size_t)tid * HW + hw];
            zrow[tid] = v;
            q[tid] = v * v;   // rounded via LDS store
        }
        __syncthreads();
        // numpy pairwise sum: 8 accumulators, exact per-accumulator order
        if (tid < 8) {
            float r = q[tid];
            for (int i = 8; i < 128; i += 8) r += q[i + tid];
            rsum[tid] = r;
        }
        __syncthreads();
        if (tid == 0)
            szs = ((rsum[0] + rsum[1]) + (rsum[2] + rsum[3]))
                + ((rsum[4] + rsum[5]) + (rsum[6] + rsum[7]));
        __syncthreads();
        const float sz32 = szs;

        // thread k owns code k: etr[d*512+k] is contiguous across lanes
        const int k = tid;
        double dot0 = 0.0, dot1 = 0.0;
        #pragma unroll 4
        for (int d = 0; d < D_DIM; d += 2) {
            dot0 += (double)etr[d * 512 + k]       * (double)zrow[d];
            dot1 += (double)etr[(d + 1) * 512 + k] * (double)zrow[d + 1];
        }
        const float dotf = (float)(dot0 + dot1);    // proxy for BLAS fp32 dot
        const float T    = sz32 + se_np[k];         // np: (A + B) broadcast
        float best  = T - 2.0f * dotf;              // np: ... - 2.0*matmul
        int   besti = k;

        // exact (val, idx) min-reduce: wave shfl then cross-wave via LDS
        #pragma unroll
        for (int off = 32; off > 0; off >>= 1) {
            const float ov = __shfl_down(best, off);
            const int   oi = __shfl_down(besti, off);
            if (ov < best || (ov == best && oi < besti)) { best = ov; besti = oi; }
        }
        if ((tid & 63) == 0) { rv[tid >> 6] = best; rix[tid >> 6] = besti; }
        __syncthreads();
        if (tid == 0) {
            #pragma unroll
            for (int w = 1; w < 8; ++w)
                if (rv[w] < best || (rv[w] == best && rix[w] < besti)) {
                    best = rv[w]; besti = rix[w];
                }
            idx_out[row] = (float)besti;
        }
    }
}

// ---------------- kernel 3: finalize loss ----------------------------------
__global__ void fin_kernel(const double* __restrict__ loss, float* __restrict__ out_loss) {
    // loss = (1 + 0.25) * mean((z_q - z)^2)
    *out_loss = (float)(*loss * 1.25 / 8388608.0);
}

extern "C" void kernel_launch(void* const* d_in, const int* in_sizes, int n_in,
                              void* d_out, int out_size, void* d_ws, size_t ws_size,
                              hipStream_t stream) {
    const float* z   = (const float*)d_in[0];
    const float* emb = (const float*)d_in[1];
    float* out      = (float*)d_out;
    float* zq       = out;               // 8388608 floats
    float* out_loss = out + 8388608;     // 1 float
    float* idx_f    = out + 8388609;     // 65536 floats (indices as fp32)

    char* ws = (char*)d_ws;
    unsigned int* flag_cnt = (unsigned int*)ws;          // offset 0
    double*       loss     = (double*)(ws + 8);          // 8 bytes
    float*        se       = (float*)(ws + 10240);       // 2048 bytes
    uint4*        ebh      = (uint4*)(ws + 16384);       // 131072 bytes
    int*          flag_list= (int*)(ws + 16384 + 262144);     // 65536 bytes
    float*        etr      = (float*)(ws + 16384 + 262144 + 65536); // 262144 B

    hipMemsetAsync(d_ws, 0, 16384, stream);
    prep_kernel <<<256,  256, 0, stream>>>(emb, etr, ebh, se);
    dist_kernel <<<2048, 256, 0, stream>>>(z, ebh, se, emb, idx_f,
                                           flag_cnt, flag_list, zq, loss);
    fixup_kernel<<<2048, 512, 0, stream>>>(z, etr, flag_cnt, flag_list, se, idx_f);
    fin_kernel  <<<1,    1,   0, stream>>>(loss, out_loss);
}

// Round 24
// 98.205 us; speedup vs baseline: 1.2099x; 1.2099x over previous
//
#include <hip/hip_runtime.h>

// VQ-VAE codebook lookup:
//   z: (64, 128, 32, 32) fp32, emb: (512, 128) fp32
//   outputs (concat in d_out, fp32): z_q (8388608) | loss (1) | indices (65536)
//
// Index output validated vs NUMPY fp32 reference (scalar threshold 10.24).
// Strategy (validated r2-r22): 1-MFMA bf16 distance argmin (zh*eh; dot error
// <= ~8e-5 << GAP_THR/2) with uint-packed keys + near-tie flags (GAP 4e-4) +
// numpy-fp32-replica fixup on flagged rows. z_q/loss from pre-fixup codes.
//
// R24: FINAL — revert to the r19/r22 configuration, the stable measured
// optimum (98.84/98.84/98.94us across 3 runs). Survey closed: 12 structures
// (tile 16..128 rows, both MFMA shapes, k/n/hybrid wave splits, LDS/reg/no
// B-staging, occ 2-4+ waves/SIMD, swizzle/setprio/unroll) all land dist in
// 55-120us; every pipelining lever was null (r14/r17/r22) or regressed via
// register pressure (r11/r20). Remaining headroom needs hand-scheduled asm.
// Pipeline: memset -> prep -> dist -> fixup -> fin (5 dispatches).

#define D_DIM 128
#define HW    1024
#define GAP_THR 4e-4f
#define FLAG_CAP 16384

typedef short short8 __attribute__((ext_vector_type(8)));
typedef float f32x16 __attribute__((ext_vector_type(16)));

union U8 { unsigned int u[4]; short8 s; uint4 q; };

__device__ __forceinline__ unsigned short f2bf(float v) {   // RNE fp32->bf16
    unsigned int u = __builtin_bit_cast(unsigned int, v);
    return (unsigned short)((u + 0x7fffu + ((u >> 16) & 1u)) >> 16);
}
__device__ __forceinline__ unsigned int umn(unsigned int a, unsigned int b) {
    return a < b ? a : b;
}
__device__ __forceinline__ unsigned int umx(unsigned int a, unsigned int b) {
    return a > b ? a : b;
}

// -------- kernel 0: fused prep: etr (all t) + esplit (t<8192) + se (t<512) --
__global__ void prep_kernel(const float* __restrict__ emb,
                            float* __restrict__ etr,
                            uint4* __restrict__ ebh,
                            float* __restrict__ se) {
    const int t = blockIdx.x * 256 + threadIdx.x;   // 0..65535

    // ---- etr[d][k] = emb[k][d] (transposed codebook, 256 KB) ----
    {
        const int k = t >> 7;
        const int d = t & 127;
        etr[d * 512 + k] = emb[t];
    }

    // ---- esplit: emb -> bf16 B-fragment images [kcol][ks][lane] (hi only) --
    if (t < 8192) {
        const int lane = t & 63;
        const int ks   = (t >> 6) & 7;
        const int kcol = t >> 9;
        const int krow = kcol * 32 + (lane & 31);
        const int d0   = ks * 16 + (lane >> 5) * 8;
        const float* ep = emb + (size_t)krow * D_DIM + d0;
        float v[8];
        #pragma unroll
        for (int j = 0; j < 8; ++j) v[j] = ep[j];
        U8 hh;
        #pragma unroll
        for (int p = 0; p < 4; ++p) {
            const unsigned short h0 = f2bf(v[2*p]), h1 = f2bf(v[2*p+1]);
            hh.u[p] = (unsigned int)h0 | ((unsigned int)h1 << 16);
        }
        ebh[t] = hh.q;
    }

    // ---- se[k] = np.sum(emb[k]**2) fp32-replica (pairwise, 8 accums) ----
    if (t < 512) {
        const float* e = emb + (size_t)t * D_DIM;
        float r[8];
        #pragma unroll
        for (int j = 0; j < 8; ++j) {
            float v = e[j];
            float p = v * v;
            asm("" : "+v"(p));   // force rounded square (no fma contraction)
            r[j] = p;
        }
        for (int i = 8; i < 128; i += 8) {
            #pragma unroll
            for (int j = 0; j < 8; ++j) {
                float v = e[i + j];
                float p = v * v;
                asm("" : "+v"(p));
                r[j] += p;
            }
        }
        se[t] = ((r[0] + r[1]) + (r[2] + r[3])) + ((r[4] + r[5]) + (r[6] + r[7]));
    }
}

// ---- kernel 1: fused dist: 2n x 2k waves, 1-MFMA argmin, fused z_q --------
// 1024 blocks x 256 thr. Wave (wn,wk): rows blk*64+wn*32..+32, kc half wk.
__launch_bounds__(256, 4)
__global__ void dist_kernel(const float* __restrict__ z,
                            const uint4* __restrict__ ebh,
                            const float* __restrict__ se_g,
                            const float* __restrict__ emb,
                            float* __restrict__ idx_out,
                            unsigned int* __restrict__ flag_cnt,
                            int* __restrict__ flag_list,
                            float* __restrict__ zq,
                            double* __restrict__ loss) {
    __shared__ unsigned int red1[2][64], red2[2][64];
    __shared__ int   li_sh[64];
    __shared__ float ept[D_DIM * 33];   // 32-row transposed emb stage
    __shared__ float lred[4];

    const int tid  = threadIdx.x;
    const int lane = tid & 63;
    const int wid  = tid >> 6;
    const int wn   = wid >> 1;          // n-subtile 0..1
    const int wk   = wid & 1;           // k-half 0..1
    const int row  = lane & 31;
    // XCD-aware swizzle (T1): 1024 blocks, 8 XCDs, bijective.
    const int bidl = (int)blockIdx.x;
    const int bid  = (bidl & 7) * 128 + (bidl >> 3);
    const int nblk = bid * 64;          // block rows (one image: 1024%64==0)
    const int bimg = nblk >> 10;
    const int hw0  = nblk & 1023;
    const int hww  = hw0 + wn * 32;

    // ---- A-frags (hi only): load z strided + pack bf16 pairs ---------------
    short8 Ah[8];
    {
        const float* zc = z + (size_t)bimg * (D_DIM * HW) + hww + row;
        #pragma unroll
        for (int ks = 0; ks < 8; ++ks) {
            const int d0 = ks * 16 + (lane >> 5) * 8;
            float v[8];
            #pragma unroll
            for (int j = 0; j < 8; ++j) v[j] = zc[(size_t)(d0 + j) * HW];
            U8 hh;
            #pragma unroll
            for (int p = 0; p < 4; ++p) {
                unsigned int hwd;
                asm("v_cvt_pk_bf16_f32 %0, %1, %2" : "=v"(hwd) : "v"(v[2*p]), "v"(v[2*p+1]));
                hh.u[p] = hwd;
            }
            Ah[ks] = hh.s;
        }
    }

    unsigned int b1[16], b2[16];
    #pragma unroll
    for (int j = 0; j < 16; ++j) { b1[j] = 0xFFFFFFFFu; b2[j] = 0xFFFFFFFFu; }

    // ---- sweep this k-half's 8 columns, staggered per block ----------------
    #pragma unroll
    for (int i = 0; i < 8; ++i) {
        const int   kc   = wk * 8 + ((i + bidl) & 7);   // de-contend L2
        const int   kgl  = kc * 32 + row;
        const float sevp = se_g[kgl] + 0.5f;
        const uint4* pbh = ebh + kc * 512 + lane;

        f32x16 acc;   // single chain, 16 AGPR
        #pragma unroll
        for (int j = 0; j < 16; ++j) acc[j] = 0.f;

        __builtin_amdgcn_s_setprio(1);
        #pragma unroll
        for (int ks = 0; ks < 8; ++ks) {
            U8 bh; bh.q = pbh[ks * 64];
            acc = __builtin_amdgcn_mfma_f32_32x32x16_bf16(Ah[ks], bh.s, acc, 0, 0, 0);
        }
        __builtin_amdgcn_s_setprio(0);

        // fold with uint-packed keys: pd = (se - 2*dot) + 0.5 in (0.25, 1)
        #pragma unroll
        for (int j = 0; j < 16; ++j) {
            const float pd = fmaf(-2.f, acc[j], sevp);
            const unsigned int key =
                (__builtin_bit_cast(unsigned int, pd) & 0xFFFFFE00u) | (unsigned int)kgl;
            const unsigned int m = umn(key, b1[j]);
            b2[j] = umn(umx(key, b1[j]), b2[j]);
            b1[j] = m;
        }
    }

    // ---- per-wave reduce over the 32 k-lanes -------------------------------
    #pragma unroll
    for (int off = 1; off <= 16; off <<= 1) {
        #pragma unroll
        for (int j = 0; j < 16; ++j) {
            const unsigned int o1 = (unsigned int)__shfl_xor((int)b1[j], off);
            const unsigned int o2 = (unsigned int)__shfl_xor((int)b2[j], off);
            const unsigned int m  = umn(b1[j], o1);
            b2[j] = umn(umx(b1[j], o1), umn(b2[j], o2));
            b1[j] = m;
        }
    }

    if ((lane & 31) == 0) {
        const int half = lane >> 5;
        #pragma unroll
        for (int j = 0; j < 16; ++j) {
            // C/D layout (m74/m101): row = (reg&3) + 8*(reg>>2) + 4*(lane>>5)
            const int r = wn * 32 + (j & 3) + 8 * (j >> 2) + 4 * half;
            red1[wk][r] = b1[j];
            red2[wk][r] = b2[j];
        }
    }
    __syncthreads();

    // ---- exact top-2 merge over the 2 k-halves (threads 0..63) -------------
    if (tid < 64) {
        const unsigned int v1a = red1[0][tid], v2a = red2[0][tid];
        const unsigned int v1b = red1[1][tid], v2b = red2[1][tid];
        const unsigned int m1 = umn(v1a, v1b);
        const unsigned int m2 = umn(umn(v2a, v2b), umx(v1a, v1b));
        const int n = nblk + tid;
        const int code = (int)(m1 & 511u);
        idx_out[n] = (float)code;
        li_sh[tid] = code;
        const float f1 = __builtin_bit_cast(float, m1 & 0xFFFFFE00u);
        const float f2 = __builtin_bit_cast(float, m2 & 0xFFFFFE00u);
        if (f2 - f1 < GAP_THR) {
            unsigned int p = atomicAdd(flag_cnt, 1u);
            if (p < FLAG_CAP) flag_list[p] = n;
        }
    }

    // ---- epilogue: 2 phases x 32 rows (r12-validated stage/write) ----------
    float lacc = 0.f;
    for (int h = 0; h < 2; ++h) {
        __syncthreads();   // li_sh ready (h=0) / previous phase readers done
        {
            const int p   = tid >> 3;         // row 0..31 (8 threads per row)
            const int sub = tid & 7;
            const float* er = emb + (size_t)li_sh[h * 32 + p] * D_DIM + sub * 16;
            #pragma unroll
            for (int j4 = 0; j4 < 4; ++j4) {
                const float4 v = *(const float4*)(er + j4 * 4);
                const int c = sub * 16 + j4 * 4;
                ept[(c + 0) * 33 + p] = v.x;
                ept[(c + 1) * 33 + p] = v.y;
                ept[(c + 2) * 33 + p] = v.z;
                ept[(c + 3) * 33 + p] = v.w;
            }
        }
        __syncthreads();
        {
            const int p  = tid & 31;          // hw position within phase tile
            const int c0 = tid >> 5;          // 0..7
            const int hwp = hw0 + h * 32 + p;
            const float* zb2 = z  + (size_t)bimg * (D_DIM * HW) + hwp;
            float*       qb  = zq + (size_t)bimg * (D_DIM * HW) + hwp;
            #pragma unroll
            for (int i = 0; i < 16; ++i) {
                const int c = c0 + i * 8;
                const float v  = ept[c * 33 + p];
                const float zv = zb2[(size_t)c * HW];
                qb[(size_t)c * HW] = v;
                const float df = v - zv;
                lacc = fmaf(df, df, lacc);
            }
        }
    }
    #pragma unroll
    for (int off = 32; off > 0; off >>= 1) lacc += __shfl_down(lacc, off);
    if (lane == 0) lred[wid] = lacc;
    __syncthreads();
    if (tid == 0)
        atomicAdd(loss, (double)(lred[0] + lred[1] + lred[2] + lred[3]));
}

// ------- kernel 1b: numpy-fp32-replica re-argmin, ONE row per block --------
// thread k owns code k; emb read via TRANSPOSED etr[d][k] -> coalesced.
__launch_bounds__(512)
__global__ void fixup_kernel(const float* __restrict__ z,
                             const float* __restrict__ etr,
                             const unsigned int* __restrict__ flag_cnt,
                             const int* __restrict__ flag_list,
                             const float* __restrict__ se_np,
                             float* __restrict__ idx_out) {
    __shared__ float zrow[D_DIM];
    __shared__ float q[D_DIM];
    __shared__ float rsum[8];
    __shared__ float szs;
    __shared__ float rv[8];
    __shared__ int   rix[8];

    const int tid = threadIdx.x;
    unsigned int cnt = *flag_cnt;
    if (cnt > FLAG_CAP) cnt = FLAG_CAP;

    for (unsigned int f = blockIdx.x; f < cnt; f += gridDim.x) {
        const int row = flag_list[f];
        const int b   = row >> 10;
        const int hw  = row & 1023;
        __syncthreads();   // previous iteration's readers done
        if (tid < D_DIM) {
            float v = z[(size_t)b * (D_DIM * HW) + (size_t)tid * HW + hw];
            zrow[tid] = v;
            q[tid] = v * v;   // rounded via LDS store
        }
        __syncthreads();
        // numpy pairwise sum: 8 accumulators, exact per-accumulator order
        if (tid < 8) {
            float r = q[tid];
            for (int i = 8; i < 128; i += 8) r += q[i + tid];
            rsum[tid] = r;
        }
        __syncthreads();
        if (tid == 0)
            szs = ((rsum[0] + rsum[1]) + (rsum[2] + rsum[3]))
                + ((rsum[4] + rsum[5]) + (rsum[6] + rsum[7]));
        __syncthreads();
        const float sz32 = szs;

        // thread k owns code k: etr[d*512+k] is contiguous across lanes
        const int k = tid;
        double dot0 = 0.0, dot1 = 0.0;
        #pragma unroll 4
        for (int d = 0; d < D_DIM; d += 2) {
            dot0 += (double)etr[d * 512 + k]       * (double)zrow[d];
            dot1 += (double)etr[(d + 1) * 512 + k] * (double)zrow[d + 1];
        }
        const float dotf = (float)(dot0 + dot1);    // proxy for BLAS fp32 dot
        const float T    = sz32 + se_np[k];         // np: (A + B) broadcast
        float best  = T - 2.0f * dotf;              // np: ... - 2.0*matmul
        int   besti = k;

        // exact (val, idx) min-reduce: wave shfl then cross-wave via LDS
        #pragma unroll
        for (int off = 32; off > 0; off >>= 1) {
            const float ov = __shfl_down(best, off);
            const int   oi = __shfl_down(besti, off);
            if (ov < best || (ov == best && oi < besti)) { best = ov; besti = oi; }
        }
        if ((tid & 63) == 0) { rv[tid >> 6] = best; rix[tid >> 6] = besti; }
        __syncthreads();
        if (tid == 0) {
            #pragma unroll
            for (int w = 1; w < 8; ++w)
                if (rv[w] < best || (rv[w] == best && rix[w] < besti)) {
                    best = rv[w]; besti = rix[w];
                }
            idx_out[row] = (float)besti;
        }
    }
}

// ---------------- kernel 3: finalize loss ----------------------------------
__global__ void fin_kernel(const double* __restrict__ loss, float* __restrict__ out_loss) {
    // loss = (1 + 0.25) * mean((z_q - z)^2)
    *out_loss = (float)(*loss * 1.25 / 8388608.0);
}

extern "C" void kernel_launch(void* const* d_in, const int* in_sizes, int n_in,
                              void* d_out, int out_size, void* d_ws, size_t ws_size,
                              hipStream_t stream) {
    const float* z   = (const float*)d_in[0];
    const float* emb = (const float*)d_in[1];
    float* out      = (float*)d_out;
    float* zq       = out;               // 8388608 floats
    float* out_loss = out + 8388608;     // 1 float
    float* idx_f    = out + 8388609;     // 65536 floats (indices as fp32)

    char* ws = (char*)d_ws;
    unsigned int* flag_cnt = (unsigned int*)ws;          // offset 0
    double*       loss     = (double*)(ws + 8);          // 8 bytes
    float*        se       = (float*)(ws + 10240);       // 2048 bytes
    uint4*        ebh      = (uint4*)(ws + 16384);       // 131072 bytes
    int*          flag_list= (int*)(ws + 16384 + 262144);     // 65536 bytes
    float*        etr      = (float*)(ws + 16384 + 262144 + 65536); // 262144 B

    hipMemsetAsync(d_ws, 0, 16384, stream);
    prep_kernel <<<256,  256, 0, stream>>>(emb, etr, ebh, se);
    dist_kernel <<<1024, 256, 0, stream>>>(z, ebh, se, emb, idx_f,
                                           flag_cnt, flag_list, zq, loss);
    fixup_kernel<<<2048, 512, 0, stream>>>(z, etr, flag_cnt, flag_list, se, idx_f);
    fin_kernel  <<<1,    1,   0, stream>>>(loss, out_loss);
}